// Round 14
// baseline (242.397 us; speedup 1.0000x reference)
//
#include <hip/hip_runtime.h>

#define BS 16
#define NN 50000
#define SEQ 9
#define IC 32
#define OC 32
#define FAN 320
#define GROUPS 64
#define MTILES_PER_B (NN / 16)          // 3125
#define TPX (2 * MTILES_PER_B)          // fallback: tiles per XCD
#define KBLK 1792                       // fallback grid
#define WPX (KBLK / 8 * 4)
#define KBLK2 2048                      // node-major main grid (8 blocks/CU)
#define NWAVE2 (KBLK2 * 4)              // 8192 waves
#define NPB2 16                         // nodes per kprep_t block
#define PBLK (NN / NPB2)                // 3125
#define WLN (SEQ * 2 * 64 * 4)          // wl uints (hi only) = 4608 -> 18432 B

typedef __attribute__((ext_vector_type(8))) short short8;
typedef __attribute__((ext_vector_type(4))) float f32x4;
typedef __attribute__((ext_vector_type(4))) unsigned uint32x4;

__device__ __forceinline__ float4 fmax4(float4 a, float4 b) {
  return make_float4(fmaxf(a.x, b.x), fmaxf(a.y, b.y), fmaxf(a.z, b.z), fmaxf(a.w, b.w));
}

// pack2: one uint = bf16 pair. A and B sides use the same pair-order ->
// any k-permutation cancels in the dot product.
__device__ __forceinline__ unsigned pk_bf16(float a, float b) {
  unsigned r;
  asm("v_cvt_pk_bf16_f32 %0, %1, %2" : "=v"(r) : "v"(a), "v"(b));
  return r;
}

__device__ __forceinline__ void split8(const float* v, unsigned* hi, unsigned* lo) {
#pragma unroll
  for (int i = 0; i < 4; i++) {
    float a = v[2 * i], b = v[2 * i + 1];
    unsigned h = pk_bf16(a, b);
    float fa = __builtin_bit_cast(float, h << 16);
    float fb = __builtin_bit_cast(float, h & 0xFFFF0000u);
    lo[i] = pk_bf16(a - fa, b - fb);
    hi[i] = h;
  }
}

union FragU { unsigned u[4]; short8 v; };

// ---------- Pass 1 (big path): transpose-convert + column-max ----------
// Block = 16 nodes x 16 batches. Thread (b = t>>4, i = t&15) reads its row
// contiguously, converts to bf16 chunks, transposes via LDS (+i swizzle), and
// the block writes the node-major xh2 blocks fully coalesced (4 x 4KB bursts).
// Column max: channel-splitting butterfly over the 16-lane i-group; each step
// KEEPS one channel-half and SENDS the other (complementary) half.
// Lane i ends holding group-max of channels {2i, 2i+1} -> coalesced float2.
__global__ __launch_bounds__(256) void kprep_t(const float* __restrict__ x,
                                               float* __restrict__ pmax,
                                               unsigned* __restrict__ xh2) {
  __shared__ uint32x4 lds4[NPB2 * 64];  // 16 KB
  int t = threadIdx.x;
  int blk = blockIdx.x;
  int n0 = blk * NPB2;
  int b = t >> 4, i = t & 15;

  const float4* xr = (const float4*)(x + ((size_t)b * NN + n0 + i) * IC);
  float4 r0 = xr[0], r1 = xr[1], r2 = xr[2], r3 = xr[3];
  float4 r4 = xr[4], r5 = xr[5], r6 = xr[6], r7 = xr[7];
  float v0[32] = {r0.x, r0.y, r0.z, r0.w, r1.x, r1.y, r1.z, r1.w,
                  r2.x, r2.y, r2.z, r2.w, r3.x, r3.y, r3.z, r3.w,
                  r4.x, r4.y, r4.z, r4.w, r5.x, r5.y, r5.z, r5.w,
                  r6.x, r6.y, r6.z, r6.w, r7.x, r7.y, r7.z, r7.w};

  // bf16 chunks -> LDS (chunk c = kg*16 + b, stored at (c + i) & 63)
  unsigned u[16];
#pragma unroll
  for (int m = 0; m < 16; m++) u[m] = pk_bf16(v0[2 * m], v0[2 * m + 1]);
#pragma unroll
  for (int kg = 0; kg < 4; kg++) {
    uint32x4 ch = {u[kg * 4], u[kg * 4 + 1], u[kg * 4 + 2], u[kg * 4 + 3]};
    lds4[i * 64 + ((kg * 16 + b + i) & 63)] = ch;
  }

  // fp32 column max over the 16-lane i-group (i = node): keep/send split.
  float v1[16];
#pragma unroll
  for (int c = 0; c < 16; c++) {
    float keep = (i & 8) ? v0[c + 16] : v0[c];
    float send = (i & 8) ? v0[c] : v0[c + 16];
    v1[c] = fmaxf(keep, __shfl_xor(send, 8));
  }
  float v2[8];
#pragma unroll
  for (int c = 0; c < 8; c++) {
    float keep = (i & 4) ? v1[c + 8] : v1[c];
    float send = (i & 4) ? v1[c] : v1[c + 8];
    v2[c] = fmaxf(keep, __shfl_xor(send, 4));
  }
  float v3[4];
#pragma unroll
  for (int c = 0; c < 4; c++) {
    float keep = (i & 2) ? v2[c + 4] : v2[c];
    float send = (i & 2) ? v2[c] : v2[c + 4];
    v3[c] = fmaxf(keep, __shfl_xor(send, 2));
  }
  float va, vb;
  {
    float keep0 = (i & 1) ? v3[2] : v3[0];
    float send0 = (i & 1) ? v3[0] : v3[2];
    float keep1 = (i & 1) ? v3[3] : v3[1];
    float send1 = (i & 1) ? v3[1] : v3[3];
    va = fmaxf(keep0, __shfl_xor(send0, 1));
    vb = fmaxf(keep1, __shfl_xor(send1, 1));
  }
  // lane i holds channels {2i, 2i+1}
  *(float2*)&pmax[((size_t)b * PBLK + blk) * 32 + 2 * i] = make_float2(va, vb);

  __syncthreads();
  uint32x4* xo = (uint32x4*)xh2 + (size_t)blk * (NPB2 * 64);
#pragma unroll
  for (int k = 0; k < 4; k++) {
    int g = k * 256 + t;
    int i2 = g >> 6, c2 = g & 63;
    xo[g] = lds4[i2 * 64 + ((c2 + i2) & 63)];
  }
}

// ---------- Pass 2 (big): blocks 0..15 reduce pmax + fold gcontrib;
//                          blocks 16..20 convert W -> bf16 fragments ----------
__global__ __launch_bounds__(256) void kfuse2(const float* __restrict__ pmax,
                                              const float* __restrict__ W,
                                              const float* __restrict__ bias,
                                              float* __restrict__ gcontrib,
                                              unsigned* __restrict__ wfrag) {
  int t = threadIdx.x;
  if (blockIdx.x < BS) {
    int b = blockIdx.x;
    __shared__ float red[8][32];
    __shared__ float gmax[IC];
    int c = t & 31, part = t >> 5;
    float m = -INFINITY;
    for (int e = part; e < PBLK; e += 8)
      m = fmaxf(m, pmax[((size_t)b * PBLK + e) * 32 + c]);
    red[part][c] = m;
    __syncthreads();
    if (t < 32) {
      float mm = red[0][t];
#pragma unroll
      for (int p = 1; p < 8; p++) mm = fmaxf(mm, red[p][t]);
      gmax[t] = mm;
    }
    __syncthreads();
    if (t < OC) {
      float acc = bias[t];
#pragma unroll
      for (int cc = 0; cc < IC; cc++) acc += gmax[cc] * W[t * FAN + SEQ * IC + cc];
      gcontrib[b * OC + t] = acc;
    }
  } else {
    int slot = (blockIdx.x - BS) * 256 + t;
    if (slot >= SEQ * 2 * 64) return;
    int s = slot >> 7, rem = slot & 127;
    int n = rem >> 6, l = rem & 63;
    int o = n * 16 + (l & 15);
    int k0 = s * 32 + (l >> 4) * 8;
    const float* p = W + o * FAN + k0;
#pragma unroll
    for (int i = 0; i < 4; i++)
      wfrag[slot * 4 + i] = pk_bf16(p[2 * i], p[2 * i + 1]);
  }
}

// ---------- Main: node-major dense gather + MFMA over (batch x out) ----------
// NT stores keep the 100 MB out stream from evicting xh2 (51 MB) out of L3.
__global__ __launch_bounds__(256, 8) void kmfma_nm(const unsigned* __restrict__ xh2,
                                                   const int* __restrict__ idx,
                                                   const float* __restrict__ gcontrib,
                                                   const unsigned* __restrict__ wfrag,
                                                   float* __restrict__ out) {
  __shared__ __align__(16) unsigned wl[WLN]; // 18432 B -> 8 blocks/CU
  int t = threadIdx.x;
  for (int i = t; i < WLN; i += 256) wl[i] = wfrag[i];
  __syncthreads();

  int wid = t >> 6, l = t & 63;
  int b = l & 15, kg = l >> 4;
  f32x4 gc0 = *(const f32x4*)&gcontrib[b * OC + kg * 4];
  f32x4 gc1 = *(const f32x4*)&gcontrib[b * OC + 16 + kg * 4];
  size_t outb = (size_t)b * NN;

  int w = __builtin_amdgcn_readfirstlane(blockIdx.x * 4 + wid);
  for (int n = w; n < NN; n += NWAVE2) {
    const int* ip = idx + n * SEQ;   // n wave-uniform -> scalar reads
    int j[SEQ];
#pragma unroll
    for (int s = 0; s < SEQ; s++) j[s] = ip[s];

    uint32x4 g[SEQ];                 // statically indexed (fully unrolled)
#pragma unroll
    for (int s = 0; s < SEQ; s++)
      g[s] = *(const uint32x4*)(xh2 + (size_t)j[s] * 256 + l * 4);

    f32x4 acc0 = {0.f, 0.f, 0.f, 0.f};
    f32x4 acc1 = {0.f, 0.f, 0.f, 0.f};
#pragma unroll
    for (int s = 0; s < SEQ; s++) {
      short8 a = __builtin_bit_cast(short8, g[s]);
      short8 w0 = *(const short8*)&wl[(s * 2 + 0) * 256 + (l << 2)];
      short8 w1 = *(const short8*)&wl[(s * 2 + 1) * 256 + (l << 2)];
      // swapped operands: D col = batch (lane&15), row = o ((lane>>4)*4+reg)
      acc0 = __builtin_amdgcn_mfma_f32_16x16x32_bf16(w0, a, acc0, 0, 0, 0);
      acc1 = __builtin_amdgcn_mfma_f32_16x16x32_bf16(w1, a, acc1, 0, 0, 0);
    }

    float* op = out + (outb + n) * OC;
    __builtin_nontemporal_store(acc0 + gc0, (f32x4*)(op + kg * 4));
    __builtin_nontemporal_store(acc1 + gc1, (f32x4*)(op + 16 + kg * 4));
  }
}

// ---------- Fallback path (small ws): round-8-style, fp32 gather + split-A ----------
__global__ __launch_bounds__(256) void kprep_fb(const float* __restrict__ x,
                                                float* __restrict__ partial) {
  int bg = blockIdx.x;
  int b = bg & 15, g = bg >> 4;
  int t = threadIdx.x;
  int q = t & 7, r = t >> 3;
  const float4* xb = (const float4*)(x + (size_t)b * NN * IC);
  float4 m = make_float4(-INFINITY, -INFINITY, -INFINITY, -INFINITY);
  for (int n = g * 32 + r; n < NN; n += GROUPS * 32) m = fmax4(m, xb[n * 8 + q]);
  __shared__ float4 sm[32][8];
  sm[r][q] = m;
  __syncthreads();
  for (int s = 16; s >= 1; s >>= 1) {
    if (r < s) sm[r][q] = fmax4(sm[r][q], sm[r + s][q]);
    __syncthreads();
  }
  if (t < 8) ((float4*)(partial + bg * IC))[t] = sm[0][t];
}

__global__ __launch_bounds__(256) void kfuse_fb(const float* __restrict__ partial,
                                                const float* __restrict__ W,
                                                const float* __restrict__ bias,
                                                float* __restrict__ gcontrib,
                                                unsigned* __restrict__ wfrag) {
  int t = threadIdx.x;
  if (blockIdx.x < BS) {
    int b = blockIdx.x;
    __shared__ float gmax[IC];
    if (t < IC) {
      float m = -INFINITY;
      for (int g = 0; g < GROUPS; g++) m = fmaxf(m, partial[(g * 16 + b) * IC + t]);
      gmax[t] = m;
    }
    __syncthreads();
    if (t < OC) {
      float acc = bias[t];
#pragma unroll
      for (int c = 0; c < IC; c++) acc += gmax[c] * W[t * FAN + SEQ * IC + c];
      gcontrib[b * OC + t] = acc;
    }
  } else {
    int slot = (blockIdx.x - BS) * 256 + t;
    if (slot >= SEQ * 2 * 64) return;
    int s = slot >> 7, rem = slot & 127;
    int n = rem >> 6, l = rem & 63;
    int o = n * 16 + (l & 15);
    int k0 = s * 32 + (l >> 4) * 8;
    const float* p = W + o * FAN + k0;
#pragma unroll
    for (int i = 0; i < 4; i++)
      wfrag[slot * 4 + i] = pk_bf16(p[2 * i], p[2 * i + 1]);
  }
}

__global__ __launch_bounds__(256, 8) void kmfma_f32(const float* __restrict__ x,
                                                    const int* __restrict__ idx,
                                                    const float* __restrict__ gcontrib,
                                                    const unsigned* __restrict__ wfrag,
                                                    float* __restrict__ out) {
  __shared__ __align__(16) unsigned wl[WLN];
  int t = threadIdx.x;
  for (int i = t; i < WLN; i += 256) wl[i] = wfrag[i];
  __syncthreads();

  int bid = blockIdx.x;
  int xcd = bid & 7, slot = bid >> 3;
  int wid = t >> 6, l = t & 63;
  int ws = slot * 4 + wid;
  int lane_lo = l & 15, kg = l >> 4;

  for (int tt = ws; tt < TPX; tt += WPX) {
    int bloc = tt >= MTILES_PER_B;
    int loc = tt - bloc * MTILES_PER_B;
    int b = xcd + 8 * bloc;
    int nb = loc * 16;
    const float* xb = x + (size_t)b * NN * IC;

    int j[SEQ];
    const int* ip = idx + (nb + lane_lo) * SEQ;
#pragma unroll
    for (int s = 0; s < SEQ; s++) j[s] = ip[s];

    f32x4 acc0 = {0.f, 0.f, 0.f, 0.f};
    f32x4 acc1 = {0.f, 0.f, 0.f, 0.f};
#pragma unroll
    for (int s = 0; s < SEQ; s++) {
      const float4* row = (const float4*)(xb + (size_t)j[s] * IC + kg * 8);
      float4 q0 = row[0], q1 = row[1];
      float v[8] = {q0.x, q0.y, q0.z, q0.w, q1.x, q1.y, q1.z, q1.w};
      FragU ah, al;
      split8(v, ah.u, al.u);
      short8 bh0 = *(const short8*)&wl[(s * 2 + 0) * 256 + (l << 2)];
      short8 bh1 = *(const short8*)&wl[(s * 2 + 1) * 256 + (l << 2)];
      acc0 = __builtin_amdgcn_mfma_f32_16x16x32_bf16(ah.v, bh0, acc0, 0, 0, 0);
      acc0 = __builtin_amdgcn_mfma_f32_16x16x32_bf16(al.v, bh0, acc0, 0, 0, 0);
      acc1 = __builtin_amdgcn_mfma_f32_16x16x32_bf16(ah.v, bh1, acc1, 0, 0, 0);
      acc1 = __builtin_amdgcn_mfma_f32_16x16x32_bf16(al.v, bh1, acc1, 0, 0, 0);
    }

    float g0 = gcontrib[b * OC + lane_lo];
    float g1 = gcontrib[b * OC + 16 + lane_lo];
#pragma unroll
    for (int jj = 0; jj < 4; jj++) {
      size_t o = ((size_t)b * NN + nb + kg * 4 + jj) * OC;
      __builtin_nontemporal_store(acc0[jj] + g0, &out[o + lane_lo]);
      __builtin_nontemporal_store(acc1[jj] + g1, &out[o + 16 + lane_lo]);
    }
  }
}

extern "C" void kernel_launch(void* const* d_in, const int* in_sizes, int n_in,
                              void* d_out, int out_size, void* d_ws, size_t ws_size,
                              hipStream_t stream) {
  const float* x = (const float*)d_in[0];
  const int* idx = (const int*)d_in[1];
  const float* W = (const float*)d_in[2];
  const float* bias = (const float*)d_in[3];
  float* out = (float*)d_out;

  const size_t xh_bytes = (size_t)NN * 256 * sizeof(unsigned);        // 51.2 MB
  const size_t pmax_bytes = (size_t)BS * PBLK * 32 * sizeof(float);   // 6.4 MB
  const size_t tail = (size_t)BS * OC * 4 + (size_t)WLN * 4 + 1024;
  bool big = ws_size >= xh_bytes + pmax_bytes + tail;

  if (big) {
    unsigned* xh2 = (unsigned*)d_ws;
    float* pmax = (float*)((char*)d_ws + xh_bytes);
    float* gcontrib = (float*)((char*)d_ws + xh_bytes + pmax_bytes);
    unsigned* wfrag = (unsigned*)(gcontrib + BS * OC);
    kprep_t<<<PBLK, 256, 0, stream>>>(x, pmax, xh2);
    kfuse2<<<BS + 5, 256, 0, stream>>>(pmax, W, bias, gcontrib, wfrag);
    kmfma_nm<<<KBLK2, 256, 0, stream>>>(xh2, idx, gcontrib, wfrag, out);
  } else {
    float* partial = (float*)d_ws;
    float* gcontrib = partial + BS * GROUPS * IC;
    unsigned* wfrag = (unsigned*)(gcontrib + BS * OC);
    kprep_fb<<<BS * GROUPS, 256, 0, stream>>>(x, partial);
    kfuse_fb<<<BS + 5, 256, 0, stream>>>(partial, W, bias, gcontrib, wfrag);
    kmfma_f32<<<KBLK, 256, 0, stream>>>(x, idx, gcontrib, wfrag, out);
  }
}

// Round 17
// 172.180 us; speedup vs baseline: 1.4078x; 1.4078x over previous
//
#include <hip/hip_runtime.h>

#define BS 16
#define NN 50000
#define SEQ 9
#define IC 32
#define OC 32
#define FAN 320
#define GROUPS 64
#define MTILES_PER_B (NN / 16)          // 3125
#define TPX (2 * MTILES_PER_B)          // fallback: tiles per XCD
#define KBLK 1792                       // fallback grid
#define WPX (KBLK / 8 * 4)
#define KBLK2 2048                      // node-major main grid (8 blocks/CU by LDS)
#define NWAVE2 (KBLK2 * 4)              // 8192 waves
#define NPB2 16                         // nodes per kprep_t block
#define PBLK (NN / NPB2)                // 3125
#define WLN (SEQ * 2 * 64 * 4)          // wl uints (hi only) = 4608 -> 18432 B

typedef __attribute__((ext_vector_type(8))) short short8;
typedef __attribute__((ext_vector_type(4))) float f32x4;
typedef __attribute__((ext_vector_type(4))) unsigned uint32x4;

__device__ __forceinline__ float4 fmax4(float4 a, float4 b) {
  return make_float4(fmaxf(a.x, b.x), fmaxf(a.y, b.y), fmaxf(a.z, b.z), fmaxf(a.w, b.w));
}

// pack2: one uint = bf16 pair. A and B sides use the same pair-order ->
// any k-permutation cancels in the dot product.
__device__ __forceinline__ unsigned pk_bf16(float a, float b) {
  unsigned r;
  asm("v_cvt_pk_bf16_f32 %0, %1, %2" : "=v"(r) : "v"(a), "v"(b));
  return r;
}

__device__ __forceinline__ void split8(const float* v, unsigned* hi, unsigned* lo) {
#pragma unroll
  for (int i = 0; i < 4; i++) {
    float a = v[2 * i], b = v[2 * i + 1];
    unsigned h = pk_bf16(a, b);
    float fa = __builtin_bit_cast(float, h << 16);
    float fb = __builtin_bit_cast(float, h & 0xFFFF0000u);
    lo[i] = pk_bf16(a - fa, b - fb);
    hi[i] = h;
  }
}

union FragU { unsigned u[4]; short8 v; };

// ---------- Pass 1 (big path): transpose-convert + column-max ----------
// Block = 16 nodes x 16 batches. Thread (b = t>>4, i = t&15) reads its row
// contiguously, converts to bf16 chunks, transposes via LDS (+i swizzle), and
// the block writes the node-major xh2 blocks fully coalesced (4 x 4KB bursts).
// Column max: keep/send butterfly over the 16-lane i-group (r13-verified).
__global__ __launch_bounds__(256) void kprep_t(const float* __restrict__ x,
                                               float* __restrict__ pmax,
                                               unsigned* __restrict__ xh2) {
  __shared__ uint32x4 lds4[NPB2 * 64];  // 16 KB
  int t = threadIdx.x;
  int blk = blockIdx.x;
  int n0 = blk * NPB2;
  int b = t >> 4, i = t & 15;

  const float4* xr = (const float4*)(x + ((size_t)b * NN + n0 + i) * IC);
  float4 r0 = xr[0], r1 = xr[1], r2 = xr[2], r3 = xr[3];
  float4 r4 = xr[4], r5 = xr[5], r6 = xr[6], r7 = xr[7];
  float v0[32] = {r0.x, r0.y, r0.z, r0.w, r1.x, r1.y, r1.z, r1.w,
                  r2.x, r2.y, r2.z, r2.w, r3.x, r3.y, r3.z, r3.w,
                  r4.x, r4.y, r4.z, r4.w, r5.x, r5.y, r5.z, r5.w,
                  r6.x, r6.y, r6.z, r6.w, r7.x, r7.y, r7.z, r7.w};

  // bf16 chunks -> LDS (chunk c = kg*16 + b, stored at (c + i) & 63)
  unsigned u[16];
#pragma unroll
  for (int m = 0; m < 16; m++) u[m] = pk_bf16(v0[2 * m], v0[2 * m + 1]);
#pragma unroll
  for (int kg = 0; kg < 4; kg++) {
    uint32x4 ch = {u[kg * 4], u[kg * 4 + 1], u[kg * 4 + 2], u[kg * 4 + 3]};
    lds4[i * 64 + ((kg * 16 + b + i) & 63)] = ch;
  }

  // fp32 column max over the 16-lane i-group (i = node): keep/send split.
  float v1[16];
#pragma unroll
  for (int c = 0; c < 16; c++) {
    float keep = (i & 8) ? v0[c + 16] : v0[c];
    float send = (i & 8) ? v0[c] : v0[c + 16];
    v1[c] = fmaxf(keep, __shfl_xor(send, 8));
  }
  float v2[8];
#pragma unroll
  for (int c = 0; c < 8; c++) {
    float keep = (i & 4) ? v1[c + 8] : v1[c];
    float send = (i & 4) ? v1[c] : v1[c + 8];
    v2[c] = fmaxf(keep, __shfl_xor(send, 4));
  }
  float v3[4];
#pragma unroll
  for (int c = 0; c < 4; c++) {
    float keep = (i & 2) ? v2[c + 4] : v2[c];
    float send = (i & 2) ? v2[c] : v2[c + 4];
    v3[c] = fmaxf(keep, __shfl_xor(send, 2));
  }
  float va, vb;
  {
    float keep0 = (i & 1) ? v3[2] : v3[0];
    float send0 = (i & 1) ? v3[0] : v3[2];
    float keep1 = (i & 1) ? v3[3] : v3[1];
    float send1 = (i & 1) ? v3[1] : v3[3];
    va = fmaxf(keep0, __shfl_xor(send0, 1));
    vb = fmaxf(keep1, __shfl_xor(send1, 1));
  }
  // lane i holds channels {2i, 2i+1}
  *(float2*)&pmax[((size_t)b * PBLK + blk) * 32 + 2 * i] = make_float2(va, vb);

  __syncthreads();
  uint32x4* xo = (uint32x4*)xh2 + (size_t)blk * (NPB2 * 64);
#pragma unroll
  for (int k = 0; k < 4; k++) {
    int g = k * 256 + t;
    int i2 = g >> 6, c2 = g & 63;
    xo[g] = lds4[i2 * 64 + ((c2 + i2) & 63)];
  }
}

// ---------- Pass 2 (big): blocks 0..15 reduce pmax + fold gcontrib;
//                          blocks 16..20 convert W -> bf16 fragments ----------
__global__ __launch_bounds__(256) void kfuse2(const float* __restrict__ pmax,
                                              const float* __restrict__ W,
                                              const float* __restrict__ bias,
                                              float* __restrict__ gcontrib,
                                              unsigned* __restrict__ wfrag) {
  int t = threadIdx.x;
  if (blockIdx.x < BS) {
    int b = blockIdx.x;
    __shared__ float red[8][32];
    __shared__ float gmax[IC];
    int c = t & 31, part = t >> 5;
    float m = -INFINITY;
    for (int e = part; e < PBLK; e += 8)
      m = fmaxf(m, pmax[((size_t)b * PBLK + e) * 32 + c]);
    red[part][c] = m;
    __syncthreads();
    if (t < 32) {
      float mm = red[0][t];
#pragma unroll
      for (int p = 1; p < 8; p++) mm = fmaxf(mm, red[p][t]);
      gmax[t] = mm;
    }
    __syncthreads();
    if (t < OC) {
      float acc = bias[t];
#pragma unroll
      for (int cc = 0; cc < IC; cc++) acc += gmax[cc] * W[t * FAN + SEQ * IC + cc];
      gcontrib[b * OC + t] = acc;
    }
  } else {
    int slot = (blockIdx.x - BS) * 256 + t;
    if (slot >= SEQ * 2 * 64) return;
    int s = slot >> 7, rem = slot & 127;
    int n = rem >> 6, l = rem & 63;
    int o = n * 16 + (l & 15);
    int k0 = s * 32 + (l >> 4) * 8;
    const float* p = W + o * FAN + k0;
#pragma unroll
    for (int i = 0; i < 4; i++)
      wfrag[slot * 4 + i] = pk_bf16(p[2 * i], p[2 * i + 1]);
  }
}

// ---------- Main: node-major dense gather + MFMA over (batch x out) ----------
// __launch_bounds__(256, 4): VGPR cap 128 -> compiler uses ~52, ZERO spill
// (r14's (256,8) capped VGPR at 32 and spilled ~84 MB/dispatch to scratch).
// Grid 2048 gives 8 blocks/CU via the 18.4 KB LDS limit.
__global__ __launch_bounds__(256, 4) void kmfma_nm(const unsigned* __restrict__ xh2,
                                                   const int* __restrict__ idx,
                                                   const float* __restrict__ gcontrib,
                                                   const unsigned* __restrict__ wfrag,
                                                   float* __restrict__ out) {
  __shared__ __align__(16) unsigned wl[WLN]; // 18432 B -> 8 blocks/CU
  int t = threadIdx.x;
  for (int i = t; i < WLN; i += 256) wl[i] = wfrag[i];
  __syncthreads();

  int wid = t >> 6, l = t & 63;
  int b = l & 15, kg = l >> 4;
  f32x4 gc0 = *(const f32x4*)&gcontrib[b * OC + kg * 4];
  f32x4 gc1 = *(const f32x4*)&gcontrib[b * OC + 16 + kg * 4];
  size_t outb = (size_t)b * NN;

  int w = __builtin_amdgcn_readfirstlane(blockIdx.x * 4 + wid);
  for (int n = w; n < NN; n += NWAVE2) {
    const int* ip = idx + n * SEQ;   // n wave-uniform -> scalar reads
    int j[SEQ];
#pragma unroll
    for (int s = 0; s < SEQ; s++) j[s] = ip[s];

    uint32x4 g[SEQ];                 // statically indexed (fully unrolled)
#pragma unroll
    for (int s = 0; s < SEQ; s++)
      g[s] = *(const uint32x4*)(xh2 + (size_t)j[s] * 256 + l * 4);

    f32x4 acc0 = {0.f, 0.f, 0.f, 0.f};
    f32x4 acc1 = {0.f, 0.f, 0.f, 0.f};
#pragma unroll
    for (int s = 0; s < SEQ; s++) {
      short8 a = __builtin_bit_cast(short8, g[s]);
      short8 w0 = *(const short8*)&wl[(s * 2 + 0) * 256 + (l << 2)];
      short8 w1 = *(const short8*)&wl[(s * 2 + 1) * 256 + (l << 2)];
      // swapped operands: D col = batch (lane&15), row = o ((lane>>4)*4+reg)
      acc0 = __builtin_amdgcn_mfma_f32_16x16x32_bf16(w0, a, acc0, 0, 0, 0);
      acc1 = __builtin_amdgcn_mfma_f32_16x16x32_bf16(w1, a, acc1, 0, 0, 0);
    }

    float* op = out + (outb + n) * OC;
    __builtin_nontemporal_store(acc0 + gc0, (f32x4*)(op + kg * 4));
    __builtin_nontemporal_store(acc1 + gc1, (f32x4*)(op + 16 + kg * 4));
  }
}

// ---------- Fallback path (small ws): round-8-style, fp32 gather + split-A ----------
__global__ __launch_bounds__(256) void kprep_fb(const float* __restrict__ x,
                                                float* __restrict__ partial) {
  int bg = blockIdx.x;
  int b = bg & 15, g = bg >> 4;
  int t = threadIdx.x;
  int q = t & 7, r = t >> 3;
  const float4* xb = (const float4*)(x + (size_t)b * NN * IC);
  float4 m = make_float4(-INFINITY, -INFINITY, -INFINITY, -INFINITY);
  for (int n = g * 32 + r; n < NN; n += GROUPS * 32) m = fmax4(m, xb[n * 8 + q]);
  __shared__ float4 sm[32][8];
  sm[r][q] = m;
  __syncthreads();
  for (int s = 16; s >= 1; s >>= 1) {
    if (r < s) sm[r][q] = fmax4(sm[r][q], sm[r + s][q]);
    __syncthreads();
  }
  if (t < 8) ((float4*)(partial + bg * IC))[t] = sm[0][t];
}

__global__ __launch_bounds__(256) void kfuse_fb(const float* __restrict__ partial,
                                                const float* __restrict__ W,
                                                const float* __restrict__ bias,
                                                float* __restrict__ gcontrib,
                                                unsigned* __restrict__ wfrag) {
  int t = threadIdx.x;
  if (blockIdx.x < BS) {
    int b = blockIdx.x;
    __shared__ float gmax[IC];
    if (t < IC) {
      float m = -INFINITY;
      for (int g = 0; g < GROUPS; g++) m = fmaxf(m, partial[(g * 16 + b) * IC + t]);
      gmax[t] = m;
    }
    __syncthreads();
    if (t < OC) {
      float acc = bias[t];
#pragma unroll
      for (int c = 0; c < IC; c++) acc += gmax[c] * W[t * FAN + SEQ * IC + c];
      gcontrib[b * OC + t] = acc;
    }
  } else {
    int slot = (blockIdx.x - BS) * 256 + t;
    if (slot >= SEQ * 2 * 64) return;
    int s = slot >> 7, rem = slot & 127;
    int n = rem >> 6, l = rem & 63;
    int o = n * 16 + (l & 15);
    int k0 = s * 32 + (l >> 4) * 8;
    const float* p = W + o * FAN + k0;
#pragma unroll
    for (int i = 0; i < 4; i++)
      wfrag[slot * 4 + i] = pk_bf16(p[2 * i], p[2 * i + 1]);
  }
}

__global__ __launch_bounds__(256, 8) void kmfma_f32(const float* __restrict__ x,
                                                    const int* __restrict__ idx,
                                                    const float* __restrict__ gcontrib,
                                                    const unsigned* __restrict__ wfrag,
                                                    float* __restrict__ out) {
  __shared__ __align__(16) unsigned wl[WLN];
  int t = threadIdx.x;
  for (int i = t; i < WLN; i += 256) wl[i] = wfrag[i];
  __syncthreads();

  int bid = blockIdx.x;
  int xcd = bid & 7, slot = bid >> 3;
  int wid = t >> 6, l = t & 63;
  int ws = slot * 4 + wid;
  int lane_lo = l & 15, kg = l >> 4;

  for (int tt = ws; tt < TPX; tt += WPX) {
    int bloc = tt >= MTILES_PER_B;
    int loc = tt - bloc * MTILES_PER_B;
    int b = xcd + 8 * bloc;
    int nb = loc * 16;
    const float* xb = x + (size_t)b * NN * IC;

    int j[SEQ];
    const int* ip = idx + (nb + lane_lo) * SEQ;
#pragma unroll
    for (int s = 0; s < SEQ; s++) j[s] = ip[s];

    f32x4 acc0 = {0.f, 0.f, 0.f, 0.f};
    f32x4 acc1 = {0.f, 0.f, 0.f, 0.f};
#pragma unroll
    for (int s = 0; s < SEQ; s++) {
      const float4* row = (const float4*)(xb + (size_t)j[s] * IC + kg * 8);
      float4 q0 = row[0], q1 = row[1];
      float v[8] = {q0.x, q0.y, q0.z, q0.w, q1.x, q1.y, q1.z, q1.w};
      FragU ah, al;
      split8(v, ah.u, al.u);
      short8 bh0 = *(const short8*)&wl[(s * 2 + 0) * 256 + (l << 2)];
      short8 bh1 = *(const short8*)&wl[(s * 2 + 1) * 256 + (l << 2)];
      acc0 = __builtin_amdgcn_mfma_f32_16x16x32_bf16(ah.v, bh0, acc0, 0, 0, 0);
      acc0 = __builtin_amdgcn_mfma_f32_16x16x32_bf16(al.v, bh0, acc0, 0, 0, 0);
      acc1 = __builtin_amdgcn_mfma_f32_16x16x32_bf16(ah.v, bh1, acc1, 0, 0, 0);
      acc1 = __builtin_amdgcn_mfma_f32_16x16x32_bf16(al.v, bh1, acc1, 0, 0, 0);
    }

    float g0 = gcontrib[b * OC + lane_lo];
    float g1 = gcontrib[b * OC + 16 + lane_lo];
#pragma unroll
    for (int jj = 0; jj < 4; jj++) {
      size_t o = ((size_t)b * NN + nb + kg * 4 + jj) * OC;
      __builtin_nontemporal_store(acc0[jj] + g0, &out[o + lane_lo]);
      __builtin_nontemporal_store(acc1[jj] + g1, &out[o + 16 + lane_lo]);
    }
  }
}

extern "C" void kernel_launch(void* const* d_in, const int* in_sizes, int n_in,
                              void* d_out, int out_size, void* d_ws, size_t ws_size,
                              hipStream_t stream) {
  const float* x = (const float*)d_in[0];
  const int* idx = (const int*)d_in[1];
  const float* W = (const float*)d_in[2];
  const float* bias = (const float*)d_in[3];
  float* out = (float*)d_out;

  const size_t xh_bytes = (size_t)NN * 256 * sizeof(unsigned);        // 51.2 MB
  const size_t pmax_bytes = (size_t)BS * PBLK * 32 * sizeof(float);   // 6.4 MB
  const size_t tail = (size_t)BS * OC * 4 + (size_t)WLN * 4 + 1024;
  bool big = ws_size >= xh_bytes + pmax_bytes + tail;

  if (big) {
    unsigned* xh2 = (unsigned*)d_ws;
    float* pmax = (float*)((char*)d_ws + xh_bytes);
    float* gcontrib = (float*)((char*)d_ws + xh_bytes + pmax_bytes);
    unsigned* wfrag = (unsigned*)(gcontrib + BS * OC);
    kprep_t<<<PBLK, 256, 0, stream>>>(x, pmax, xh2);
    kfuse2<<<BS + 5, 256, 0, stream>>>(pmax, W, bias, gcontrib, wfrag);
    kmfma_nm<<<KBLK2, 256, 0, stream>>>(xh2, idx, gcontrib, wfrag, out);
  } else {
    float* partial = (float*)d_ws;
    float* gcontrib = partial + BS * GROUPS * IC;
    unsigned* wfrag = (unsigned*)(gcontrib + BS * OC);
    kprep_fb<<<BS * GROUPS, 256, 0, stream>>>(x, partial);
    kfuse_fb<<<BS + 5, 256, 0, stream>>>(partial, W, bias, gcontrib, wfrag);
    kmfma_f32<<<KBLK, 256, 0, stream>>>(x, idx, gcontrib, wfrag, out);
  }
}